// Round 8
// baseline (416.478 us; speedup 1.0000x reference)
//
#include <hip/hip_runtime.h>
#include <stdint.h>

#define NSAMP 16384
#define NSITE 2048
#define BM 128
#define BN 256
#define BK 32
#define NT_M (NSAMP / BM)   // 128
#define NT_N (NSITE / BN)   // 8

typedef _Float16 f16x8 __attribute__((ext_vector_type(8)));
typedef float f32x16 __attribute__((ext_vector_type(16)));

__device__ __forceinline__ unsigned short f2h(float f) {
  _Float16 h = (_Float16)f;
  return __builtin_bit_cast(unsigned short, h);
}
__device__ __forceinline__ float h2f(unsigned short u) {
  return (float)__builtin_bit_cast(_Float16, u);
}

__device__ __forceinline__ void gload_lds16(const void* g, void* l) {
  __builtin_amdgcn_global_load_lds(
      (const __attribute__((address_space(1))) void*)g,
      (__attribute__((address_space(3))) void*)l, 16, 0, 0);
}

#define SBAR() __builtin_amdgcn_sched_barrier(0)
#define BAR()  do { SBAR(); __builtin_amdgcn_s_barrier(); SBAR(); } while (0)
#define WLGKM(N) do { asm volatile("s_waitcnt lgkmcnt(" #N ")" ::: "memory"); SBAR(); } while (0)
#define WVM(N)   do { asm volatile("s_waitcnt vmcnt(" #N ")" ::: "memory"); SBAR(); } while (0)

// single-plane fp16 W: W[j][i] = fp16(kernel[tri(j,i)]) for i<j else 0
__global__ void build_w_kernel(const float* __restrict__ kern,
                               unsigned short* __restrict__ W) {
  int idx = blockIdx.x * blockDim.x + threadIdx.x;
  int j = idx >> 11;
  int i = idx & (NSITE - 1);
  float v = 0.0f;
  if (i < j) v = kern[j * (j - 1) / 2 + i];
  W[idx] = f2h(v);
}

// fp16 X from f32 x, 4 elems/thread
__global__ void build_x_kernel(const float* __restrict__ x,
                               unsigned short* __restrict__ X) {
  int idx = blockIdx.x * blockDim.x + threadIdx.x;
  const float4 v = reinterpret_cast<const float4*>(x)[idx];
  reinterpret_cast<ushort4*>(X)[idx] =
      make_ushort4(f2h(v.x), f2h(v.y), f2h(v.z), f2h(v.w));
}

// 128x256 block, 4 waves (2Mx2N, wave tile 64x128), BK=32, 32x32x16 fp16 MFMA.
// Fragment-major LDS: A frag f=(rowblock*2+ksub) at f*1024; B frag
// f=(colblock*2+ksub) at 8192+f*1024. Reads are uniform-base + lane*16
// (zero bank conflicts). Per wave-step: 12 ds_read_b128 : 16 MFMA.
// Ring-3 of 24KB slots = 72KB -> 2 blocks/CU. Stage t+2, wait vmcnt(6).
template <int EPI>
__global__ __launch_bounds__(256, 2) void gemm_pass(
    const unsigned short* __restrict__ A, const unsigned short* __restrict__ W,
    const unsigned short* __restrict__ X, unsigned short* __restrict__ P,
    float* __restrict__ out) {
  __shared__ unsigned short lds[3][12288];  // 3 x 24KB

  const int bid = blockIdx.x;
  // round 1 (bid<512): nt = 7,6,5,4 ; round 2: nt = 3,2,1,0
  const int g = (bid >> 7) & 3;
  const int nt = (bid >> 9) ? (3 - g) : (7 - g);
  const int mt = bid & 127;
  const int m0 = mt * BM;
  const int n0 = nt * BN;

  const int tid = threadIdx.x;   // 0..255
  const int lane = tid & 63;
  const int wid = tid >> 6;      // 0..3
  const int wm = wid >> 1;       // 0..1: rows wm*64..
  const int wn = wid & 1;        // 0..1: cols wn*128..
  const int l32 = lane & 31;
  const int hi2 = lane >> 5;
  const int lbo = lane * 16;

  f32x16 acc[2][4] = {};         // [mb][nb], 128 VGPRs

  const int nkt = 8 * (nt + 1);  // strictly-lower-tri K cut

  // staging sources: round r stages frags r*4 + (tid>>6); frag f=(blk*2+s):
  // lane sl holds [blk*32 + (sl&31)][s*16 + (sl>>5)*8 ..+8]
  const int fsub = tid >> 6;
  const int sl = tid & 63;
  auto srcoff = [&](int f, int rbase) {
    const int blk = f >> 1, s = f & 1;
    return (size_t)(rbase + blk * 32 + (sl & 31)) * NSITE + s * 16 + (sl >> 5) * 8;
  };
  const unsigned short* sA0 = A + srcoff(fsub, m0);
  const unsigned short* sA1 = A + srcoff(4 + fsub, m0);
  const unsigned short* sB0 = W + srcoff(fsub, n0);
  const unsigned short* sB1 = W + srcoff(4 + fsub, n0);
  const unsigned short* sB2 = W + srcoff(8 + fsub, n0);
  const unsigned short* sB3 = W + srcoff(12 + fsub, n0);

  auto STAGE = [&](int kidx, int slot) {
    char* Ls = (char*)&lds[slot][0];
    const int ko = kidx * BK;
    gload_lds16(sA0 + ko, Ls + tid * 16);
    gload_lds16(sA1 + ko, Ls + 4096 + tid * 16);
    gload_lds16(sB0 + ko, Ls + 8192 + tid * 16);
    gload_lds16(sB1 + ko, Ls + 12288 + tid * 16);
    gload_lds16(sB2 + ko, Ls + 16384 + tid * 16);
    gload_lds16(sB3 + ko, Ls + 20480 + tid * 16);
  };

  STAGE(0, 0);
  STAGE(1, 1);
  WVM(6);  // slot0 landed (slot1 may still fly)
  BAR();

  int slot = 0, slot2 = 2;
  for (int t = 0; t < nkt; ++t) {
    const char* Ls = (const char*)&lds[slot][0];
    f16x8 fa[2][2], fb[2][4];  // [ksub][mb/nb]
    // ksub0 reads (6)
#pragma unroll
    for (int mb = 0; mb < 2; ++mb)
      fa[0][mb] = *(const f16x8*)(Ls + ((wm * 2 + mb) * 2 + 0) * 1024 + lbo);
#pragma unroll
    for (int nb = 0; nb < 4; ++nb)
      fb[0][nb] = *(const f16x8*)(Ls + 8192 + ((wn * 4 + nb) * 2 + 0) * 1024 + lbo);
    SBAR();
    if (t + 2 < nkt) STAGE(t + 2, slot2);
    // ksub1 reads (6)
#pragma unroll
    for (int mb = 0; mb < 2; ++mb)
      fa[1][mb] = *(const f16x8*)(Ls + ((wm * 2 + mb) * 2 + 1) * 1024 + lbo);
#pragma unroll
    for (int nb = 0; nb < 4; ++nb)
      fb[1][nb] = *(const f16x8*)(Ls + 8192 + ((wn * 4 + nb) * 2 + 1) * 1024 + lbo);
    WLGKM(6);  // ksub0 frags ready
    __builtin_amdgcn_s_setprio(1);
#pragma unroll
    for (int mb = 0; mb < 2; ++mb)
#pragma unroll
      for (int nb = 0; nb < 4; ++nb)
        acc[mb][nb] = __builtin_amdgcn_mfma_f32_32x32x16_f16(fa[0][mb], fb[0][nb],
                                                             acc[mb][nb], 0, 0, 0);
    WLGKM(0);  // ksub1 frags ready
#pragma unroll
    for (int mb = 0; mb < 2; ++mb)
#pragma unroll
      for (int nb = 0; nb < 4; ++nb)
        acc[mb][nb] = __builtin_amdgcn_mfma_f32_32x32x16_f16(fa[1][mb], fb[1][nb],
                                                             acc[mb][nb], 0, 0, 0);
    __builtin_amdgcn_s_setprio(0);
    if (t + 1 < nkt) {
      if (t + 2 < nkt) { WVM(6); } else { WVM(0); }  // slot t+1 landed
      BAR();
    }
    slot = (slot == 2) ? 0 : slot + 1;
    slot2 = (slot2 == 2) ? 0 : slot2 + 1;
  }

  // C/D layout 32x32: col = lane&31, row = (reg&3)+8*(reg>>2)+4*(lane>>5)
  if (EPI == 0) {
#pragma unroll
    for (int m = 0; m < 2; ++m)
#pragma unroll
      for (int n = 0; n < 4; ++n)
#pragma unroll
        for (int r = 0; r < 16; ++r) {
          const int row = (r & 3) + 8 * (r >> 2) + 4 * hi2;
          const int grow = m0 + wm * 64 + m * 32 + row;
          const int gcol = n0 + wn * 128 + n * 32 + l32;
          const size_t off = (size_t)grow * NSITE + gcol;
          P[off] = f2h(acc[m][n][r] * h2f(X[off]));
        }
  } else {
#pragma unroll
    for (int m = 0; m < 2; ++m)
#pragma unroll
      for (int r = 0; r < 16; ++r) {
        const int row = (r & 3) + 8 * (r >> 2) + 4 * hi2;
        const int grow = m0 + wm * 64 + m * 32 + row;
        const size_t base = (size_t)grow * NSITE + n0 + wn * 128 + l32;
        float s = acc[m][0][r] * h2f(X[base]) + acc[m][1][r] * h2f(X[base + 32]) +
                  acc[m][2][r] * h2f(X[base + 64]) + acc[m][3][r] * h2f(X[base + 96]);
        s += __shfl_xor(s, 1);
        s += __shfl_xor(s, 2);
        s += __shfl_xor(s, 4);
        s += __shfl_xor(s, 8);
        s += __shfl_xor(s, 16);
        if (l32 == 0) atomicAdd(&out[grow], s);
      }
  }
}

extern "C" void kernel_launch(void* const* d_in, const int* in_sizes, int n_in,
                              void* d_out, int out_size, void* d_ws, size_t ws_size,
                              hipStream_t stream) {
  const float* x = (const float*)d_in[0];
  const float* kern = (const float*)d_in[1];
  float* out = (float*)d_out;

  unsigned short* W  = (unsigned short*)d_ws;            // N*N fp16
  unsigned short* X  = W + (size_t)NSITE * NSITE;        // NS*N fp16
  unsigned short* P1 = X + (size_t)NSAMP * NSITE;        // NS*N fp16
  unsigned short* P2 = P1 + (size_t)NSAMP * NSITE;       // NS*N fp16

  hipMemsetAsync(d_out, 0, (size_t)NSAMP * sizeof(float), stream);
  build_w_kernel<<<(NSITE * NSITE) / 256, 256, 0, stream>>>(kern, W);
  build_x_kernel<<<(NSAMP * NSITE / 4) / 256, 256, 0, stream>>>(x, X);

  // pass 1: z1 = x @ W^T ; P1 = fp16(z1 * x)
  gemm_pass<0><<<NT_M * NT_N, 256, 0, stream>>>(X, W, X, P1, nullptr);
  // pass 2: z2 = P1 @ W^T ; P2 = fp16(z2 * x)
  gemm_pass<0><<<NT_M * NT_N, 256, 0, stream>>>(P1, W, X, P2, nullptr);
  // pass 3: z3 = P2 @ W^T ; out[n] = sum_j z3 * x
  gemm_pass<1><<<NT_M * NT_N, 256, 0, stream>>>(P2, W, X, nullptr, out);
}